// Round 13
// baseline (142.498 us; speedup 1.0000x reference)
//
#include <hip/hip_runtime.h>

// Problem constants
#define NP     64      // params per cell
#define NC     2080    // NP*(NP+1)/2 packed upper-tri coefficients
#define NCELLS 4096    // 64*64 grid cells
#define NB     32      // batch
#define CELLS_PER_BLOCK 4                   // one cell per wave
#define TOTALB (NCELLS / CELLS_PER_BLOCK)   // 1024 blocks

typedef short bf16x8  __attribute__((ext_vector_type(8)));  // MFMA A/B frag
typedef short short4v __attribute__((ext_vector_type(4)));  // one ds_read_b64
typedef float f32x16  __attribute__((ext_vector_type(16))); // MFMA accumulator

// f32 -> bf16 bits, round-to-nearest-even.
__device__ __forceinline__ short f2bf(float f) {
  unsigned u = __float_as_uint(f);
  u += 0x7fffu + ((u >> 16) & 1u);
  return (short)(u >> 16);
}

// Swizzled physical i-index for A_T[j][i]: XOR bits[5:2] with j&15.
__device__ __forceinline__ int swz(int j, int i) { return i ^ ((j & 15) << 2); }

// DPP row_ror sum; ctrl must be an ICE -> template parameter.
template <int CTRL>
__device__ __forceinline__ float ror_add(float v) {
  int t = __builtin_amdgcn_update_dpp(0, __float_as_int(v), CTRL, 0xf, 0xf, true);
  return v + __int_as_float(t);
}

// R11 phase-1 (proven: 21.8us, absmax 16) + fused last-block finisher.
// Election correctness: cnt is hipMemsetAsync'd to 0 at the start of every
// kernel_launch (graph-captured as a memset node, so every timed replay
// re-arms it). atomicAdd is device-scope (G12); last arrival sees
// old == TOTALB-1 AFTER all other blocks' ws stores + release fences.
__global__ __launch_bounds__(256, 4) void poly_fused_kernel(
    const float* __restrict__ param,   // [NB][NCELLS][NP]
    const float* __restrict__ coeffs,  // [NCELLS][NC]
    float* __restrict__ ws,            // [NB][TOTALB]
    unsigned* __restrict__ cnt,        // zeroed each launch via memset node
    float* __restrict__ out) {         // [NB]
  __shared__ __align__(16) short scoefT[CELLS_PER_BLOCK][NP][NP];  // 32 KB
  __shared__ float sred[CELLS_PER_BLOCK][NB];
  __shared__ float fred[NB][8];
  __shared__ unsigned is_last;

  const int tid  = threadIdx.x;
  const int wave = tid >> 6;
  const int lane = tid & 63;
  const int lo5  = lane & 31;  // A-row b; B/C column j (within half)
  const int hi   = lane >> 5;
  const int cell = blockIdx.x * CELLS_PER_BLOCK + wave;

  // ---- Zero-fill this wave's A_T tile (below-diagonal stays 0).
  {
    int4* z = reinterpret_cast<int4*>(&scoefT[wave][0][0]);
    const int4 zero = {0, 0, 0, 0};
#pragma unroll
    for (int k = 0; k < 8; ++k) z[k * 64 + lane] = zero;
  }

  // ---- Wave-private staging: packed triu f32 -> unpacked transposed bf16.
  // Linear index c -> (i,j): i from the exact identity
  // 16641 - 8*base_i = (129-2i)^2  (f32 sqrt exact at row boundaries).
  {
    const float4* gsrc =
        reinterpret_cast<const float4*>(coeffs + (size_t)cell * NC);
#pragma unroll
    for (int k = 0; k < 9; ++k) {
      const int idx = k * 64 + lane;
      if (idx < NC / 4) {
        const float4 v = gsrc[idx];
        const int c = idx * 4;
        const float fs = sqrtf((float)(16641 - 8 * c));
        int i = (int)((129.0f - fs) * 0.5f);
        int bi = 64 * i - ((i * (i - 1)) >> 1);
        if (c < bi) { --i; bi -= (64 - i); }
        else if (c >= bi + (64 - i)) { bi += (64 - i); ++i; }
        int off = c - bi;  // offset within row i
        const float vals[4] = {v.x, v.y, v.z, v.w};
#pragma unroll
        for (int d = 0; d < 4; ++d) {
          const int j = i + off;
          scoefT[wave][j][swz(j, i)] = f2bf(vals[d]);
          ++off;
          if (off == 64 - i) { ++i; off = 0; }
        }
      }
    }
  }

  // ---- A-operand fragments (global). row b = lo5,
  //      k_i = ks*16 + 4*hi + (e&3) + 8*(e>>2) (same k-map as B).
  const float* pb = param + ((size_t)lo5 * NCELLS + cell) * NP;
  bf16x8 afrag[4];
#pragma unroll
  for (int ks = 0; ks < 4; ++ks) {
#pragma unroll
    for (int eh = 0; eh < 2; ++eh) {
      const int i0 = ks * 16 + 4 * hi + 8 * eh;
      const float4 v = *reinterpret_cast<const float4*>(pb + i0);
      afrag[ks][eh * 4 + 0] = f2bf(v.x);
      afrag[ks][eh * 4 + 1] = f2bf(v.y);
      afrag[ks][eh * 4 + 2] = f2bf(v.z);
      afrag[ks][eh * 4 + 3] = f2bf(v.w);
    }
  }

  // ---- T14: issue epilogue P-loads now, consume after MFMAs.
  // C/D layout (HW-verified): col j = lane&31, row b = (r&3)+8*(r>>2)+4*hi.
  float pepi0[16], pepi1[16];
#pragma unroll
  for (int r = 0; r < 16; ++r) {
    const int b = (r & 3) + 8 * (r >> 2) + 4 * hi;
    const float* pe = param + ((size_t)b * NCELLS + cell) * NP;
    pepi0[r] = pe[lo5];
    pepi1[r] = pe[lo5 + 32];
  }

  // ---- B-operand: 16x ds_read_b64 from the transposed tile + 8 MFMAs.
  const short* swT = &scoefT[wave][0][0];
  const int jb0 = lo5 * NP;         // j = lo5
  const int jb1 = (lo5 + 32) * NP;  // j = lo5+32 (same swizzle: j&15 equal)
  f32x16 acc0, acc1;
#pragma unroll
  for (int r = 0; r < 16; ++r) { acc0[r] = 0.f; acc1[r] = 0.f; }

#pragma unroll
  for (int ks = 0; ks < 4; ++ks) {
    const int ia = ks * 16 + 4 * hi;      // eh=0 group base
    const int ib = ia + 8;                // eh=1 group base
    const short4v a0 = *reinterpret_cast<const short4v*>(swT + jb0 + swz(lo5, ia));
    const short4v a1 = *reinterpret_cast<const short4v*>(swT + jb0 + swz(lo5, ib));
    const short4v c0 = *reinterpret_cast<const short4v*>(swT + jb1 + swz(lo5, ia));
    const short4v c1 = *reinterpret_cast<const short4v*>(swT + jb1 + swz(lo5, ib));
    const bf16x8 b0 = __builtin_shufflevector(a0, a1, 0, 1, 2, 3, 4, 5, 6, 7);
    const bf16x8 b1 = __builtin_shufflevector(c0, c1, 0, 1, 2, 3, 4, 5, 6, 7);
    acc0 = __builtin_amdgcn_mfma_f32_32x32x16_bf16(afrag[ks], b0, acc0, 0, 0, 0);
    acc1 = __builtin_amdgcn_mfma_f32_32x32x16_bf16(afrag[ks], b1, acc1, 0, 0, 0);
  }

  // ---- Epilogue: dacc = D[b,j]*P[b,j] + D[b,j+32]*P[b,j+32]; reduce over j.
#pragma unroll
  for (int r = 0; r < 16; ++r) {
    float v = fmaf(acc0[r], pepi0[r], acc1[r] * pepi1[r]);
    v = ror_add<0x121>(v);
    v = ror_add<0x122>(v);
    v = ror_add<0x124>(v);
    v = ror_add<0x128>(v);
    v += __int_as_float(__builtin_amdgcn_ds_swizzle(__float_as_int(v), 0x401F));
    if (lo5 == 0) {
      const int b = (r & 3) + 8 * (r >> 2) + 4 * hi;
      sred[wave][b] = v;
    }
  }
  __syncthreads();
  if (tid < NB) {
    ws[(size_t)tid * TOTALB + blockIdx.x] =
        sred[0][tid] + sred[1][tid] + sred[2][tid] + sred[3][tid];
  }

  // ---- Last-block election (cnt starts at 0 every launch via memset node).
  __threadfence();  // release: ws stores visible before the bump
  if (tid == 0) {
    is_last = (atomicAdd(cnt, 1u) == (unsigned)(TOTALB - 1)) ? 1u : 0u;
  }
  __syncthreads();
  if (!is_last) return;
  __threadfence();  // acquire: all blocks' ws stores now visible

  // ---- Finisher: deterministic sum of ws[NB][TOTALB] -> out[NB].
  {
    const int fb = tid >> 3;  // 0..31
    const int fp = tid & 7;   // 0..7
    const float* base = ws + (size_t)fb * TOTALB + fp * (TOTALB / 8);
    float s = 0.f;
#pragma unroll 4
    for (int q = 0; q < TOTALB / 8 / 4; ++q) {
      const float4 v = reinterpret_cast<const float4*>(base)[q];
      s += (v.x + v.y) + (v.z + v.w);
    }
    fred[fb][fp] = s;
  }
  __syncthreads();
  if (tid < NB) {
    float t = 0.f;
#pragma unroll
    for (int q = 0; q < 8; ++q) t += fred[tid][q];
    out[tid] = t;
  }
}

extern "C" void kernel_launch(void* const* d_in, const int* in_sizes, int n_in,
                              void* d_out, int out_size, void* d_ws,
                              size_t ws_size, hipStream_t stream) {
  const float* param = (const float*)d_in[0];   // [32,64,64,64] f32
  const float* coeffs = (const float*)d_in[1];  // [64,64,2080] f32
  float* out = (float*)d_out;                   // [32] f32
  float* ws = (float*)d_ws;                     // [NB][TOTALB] = 128 KB
  unsigned* cnt =
      (unsigned*)((char*)d_ws + (size_t)NB * TOTALB * sizeof(float));

  // Re-arm the election counter every call (graph captures this as a
  // memset node, so each timed replay resets it deterministically).
  hipMemsetAsync(cnt, 0, sizeof(unsigned), stream);

  hipLaunchKernelGGL(poly_fused_kernel, dim3(TOTALB), dim3(256), 0, stream,
                     param, coeffs, ws, cnt, out);
}

// Round 14
// 21.686 us; speedup vs baseline: 6.5710x; 6.5710x over previous
//
#include <hip/hip_runtime.h>

// Problem constants
#define NP     64      // params per cell
#define NC     2080    // NP*(NP+1)/2 packed upper-tri coefficients
#define NCELLS 4096    // 64*64 grid cells
#define NB     32      // batch
#define CELLS_PER_BLOCK 4                   // one cell per wave
#define BLOCKS (NCELLS / CELLS_PER_BLOCK)   // 1024

typedef short bf16x8  __attribute__((ext_vector_type(8)));  // MFMA A/B frag
typedef short short4v __attribute__((ext_vector_type(4)));  // one ds_read_b64
typedef float f32x16  __attribute__((ext_vector_type(16))); // MFMA accumulator

// f32 -> bf16 bits, round-to-nearest-even.
__device__ __forceinline__ short f2bf(float f) {
  unsigned u = __float_as_uint(f);
  u += 0x7fffu + ((u >> 16) & 1u);
  return (short)(u >> 16);
}

// Swizzled physical i-index for A_T[j][i]: XOR bits[5:2] with j&15.
// Bits >=2 only => 4-aligned groups of 4 stay contiguous (ds_read_b64-able)
// and the A/B k-slot pairing is unchanged.
__device__ __forceinline__ int swz(int j, int i) { return i ^ ((j & 15) << 2); }

// DPP row_ror sum; ctrl must be an ICE -> template parameter.
template <int CTRL>
__device__ __forceinline__ float ror_add(float v) {
  int t = __builtin_amdgcn_update_dpp(0, __float_as_int(v), CTRL, 0xf, 0xf, true);
  return v + __int_as_float(t);
}

// One wave per cell. The packed-triu coeff row is unpacked ON STAGE into a
// zero-filled transposed bf16 tile A_T[j][i] in LDS (wave-private, no
// barrier), so the MFMA B-operand is 16 ds_read_b64 instead of 128
// ds_read_u16. Epilogue P loaded early (T14); j-reduction via DPP row_ror
// (VALU) + one ds_swizzle xor16.
__global__ __launch_bounds__(256, 4) void poly_mfma_kernel(
    const float* __restrict__ param,   // [NB][NCELLS][NP]
    const float* __restrict__ coeffs,  // [NCELLS][NC]
    float* __restrict__ ws) {          // [NB][BLOCKS] (transposed)
  __shared__ __align__(16) short scoefT[CELLS_PER_BLOCK][NP][NP];  // 32 KB
  __shared__ float sred[CELLS_PER_BLOCK][NB];

  const int tid  = threadIdx.x;
  const int wave = tid >> 6;
  const int lane = tid & 63;
  const int lo5  = lane & 31;  // A-row b; B/C column j (within half)
  const int hi   = lane >> 5;
  const int cell = blockIdx.x * CELLS_PER_BLOCK + wave;

  // ---- Zero-fill this wave's A_T tile (below-diagonal stays 0).
  {
    int4* z = reinterpret_cast<int4*>(&scoefT[wave][0][0]);
    const int4 zero = {0, 0, 0, 0};
#pragma unroll
    for (int k = 0; k < 8; ++k) z[k * 64 + lane] = zero;
  }

  // ---- Wave-private staging: packed triu f32 -> unpacked transposed bf16.
  // Linear index c -> (i,j): i from the exact identity
  // 16641 - 8*base_i = (129-2i)^2  (f32 sqrt exact at row boundaries).
  {
    const float4* gsrc =
        reinterpret_cast<const float4*>(coeffs + (size_t)cell * NC);
#pragma unroll
    for (int k = 0; k < 9; ++k) {
      const int idx = k * 64 + lane;
      if (idx < NC / 4) {
        const float4 v = gsrc[idx];
        const int c = idx * 4;
        const float fs = sqrtf((float)(16641 - 8 * c));
        int i = (int)((129.0f - fs) * 0.5f);
        int bi = 64 * i - ((i * (i - 1)) >> 1);
        if (c < bi) { --i; bi -= (64 - i); }
        else if (c >= bi + (64 - i)) { bi += (64 - i); ++i; }
        int off = c - bi;  // offset within row i
        const float vals[4] = {v.x, v.y, v.z, v.w};
#pragma unroll
        for (int d = 0; d < 4; ++d) {
          const int j = i + off;
          scoefT[wave][j][swz(j, i)] = f2bf(vals[d]);
          ++off;
          if (off == 64 - i) { ++i; off = 0; }
        }
      }
    }
  }

  // ---- A-operand fragments (global). row b = lo5,
  //      k_i = ks*16 + 4*hi + (e&3) + 8*(e>>2) (same k-map as B).
  const float* pb = param + ((size_t)lo5 * NCELLS + cell) * NP;
  bf16x8 afrag[4];
#pragma unroll
  for (int ks = 0; ks < 4; ++ks) {
#pragma unroll
    for (int eh = 0; eh < 2; ++eh) {
      const int i0 = ks * 16 + 4 * hi + 8 * eh;
      const float4 v = *reinterpret_cast<const float4*>(pb + i0);
      afrag[ks][eh * 4 + 0] = f2bf(v.x);
      afrag[ks][eh * 4 + 1] = f2bf(v.y);
      afrag[ks][eh * 4 + 2] = f2bf(v.z);
      afrag[ks][eh * 4 + 3] = f2bf(v.w);
    }
  }

  // ---- T14: issue epilogue P-loads now, consume after MFMAs.
  // C/D layout (HW-verified): col j = lane&31, row b = (r&3)+8*(r>>2)+4*hi.
  float pepi0[16], pepi1[16];
#pragma unroll
  for (int r = 0; r < 16; ++r) {
    const int b = (r & 3) + 8 * (r >> 2) + 4 * hi;
    const float* pe = param + ((size_t)b * NCELLS + cell) * NP;
    pepi0[r] = pe[lo5];
    pepi1[r] = pe[lo5 + 32];
  }

  // ---- B-operand: 16x ds_read_b64 from the transposed tile + 8 MFMAs.
  const short* swT = &scoefT[wave][0][0];
  const int jb0 = lo5 * NP;         // j = lo5
  const int jb1 = (lo5 + 32) * NP;  // j = lo5+32 (same swizzle: j&15 equal)
  f32x16 acc0, acc1;
#pragma unroll
  for (int r = 0; r < 16; ++r) { acc0[r] = 0.f; acc1[r] = 0.f; }

#pragma unroll
  for (int ks = 0; ks < 4; ++ks) {
    const int ia = ks * 16 + 4 * hi;      // eh=0 group base
    const int ib = ia + 8;                // eh=1 group base
    const short4v a0 = *reinterpret_cast<const short4v*>(swT + jb0 + swz(lo5, ia));
    const short4v a1 = *reinterpret_cast<const short4v*>(swT + jb0 + swz(lo5, ib));
    const short4v c0 = *reinterpret_cast<const short4v*>(swT + jb1 + swz(lo5, ia));
    const short4v c1 = *reinterpret_cast<const short4v*>(swT + jb1 + swz(lo5, ib));
    const bf16x8 b0 = __builtin_shufflevector(a0, a1, 0, 1, 2, 3, 4, 5, 6, 7);
    const bf16x8 b1 = __builtin_shufflevector(c0, c1, 0, 1, 2, 3, 4, 5, 6, 7);
    acc0 = __builtin_amdgcn_mfma_f32_32x32x16_bf16(afrag[ks], b0, acc0, 0, 0, 0);
    acc1 = __builtin_amdgcn_mfma_f32_32x32x16_bf16(afrag[ks], b1, acc1, 0, 0, 0);
  }

  // ---- Epilogue: dacc = D[b,j]*P[b,j] + D[b,j+32]*P[b,j+32]; reduce over j.
#pragma unroll
  for (int r = 0; r < 16; ++r) {
    float v = fmaf(acc0[r], pepi0[r], acc1[r] * pepi1[r]);
    // 16-lane row sum on the VALU pipe (DPP row_ror 1,2,4,8)...
    v = ror_add<0x121>(v);
    v = ror_add<0x122>(v);
    v = ror_add<0x124>(v);
    v = ror_add<0x128>(v);
    // ...then one cross-row xor16 swizzle completes the 32-lane half-sum.
    v += __int_as_float(__builtin_amdgcn_ds_swizzle(__float_as_int(v), 0x401F));
    if (lo5 == 0) {
      const int b = (r & 3) + 8 * (r >> 2) + 4 * hi;
      sred[wave][b] = v;
    }
  }
  __syncthreads();
  if (tid < NB) {
    ws[(size_t)tid * BLOCKS + blockIdx.x] =
        sred[0][tid] + sred[1][tid] + sred[2][tid] + sred[3][tid];
  }
}

// One block per b: sum ws[b][0..BLOCKS) -> out[b]. 256 threads x 1 float4.
__global__ void poly_reduce_kernel(const float* __restrict__ ws,
                                   float* __restrict__ out) {
  const int b = blockIdx.x;
  const int tid = threadIdx.x;
  const float4 v =
      reinterpret_cast<const float4*>(ws + (size_t)b * BLOCKS)[tid];
  float s = (v.x + v.y) + (v.z + v.w);
#pragma unroll
  for (int off = 1; off <= 32; off <<= 1) s += __shfl_xor(s, off, 64);
  __shared__ float sp[4];
  if ((tid & 63) == 0) sp[tid >> 6] = s;
  __syncthreads();
  if (tid == 0) out[b] = (sp[0] + sp[1]) + (sp[2] + sp[3]);
}

extern "C" void kernel_launch(void* const* d_in, const int* in_sizes, int n_in,
                              void* d_out, int out_size, void* d_ws,
                              size_t ws_size, hipStream_t stream) {
  const float* param = (const float*)d_in[0];   // [32,64,64,64] f32
  const float* coeffs = (const float*)d_in[1];  // [64,64,2080] f32
  float* out = (float*)d_out;                   // [32] f32
  float* ws = (float*)d_ws;                     // NB*BLOCKS*4 = 128 KB

  hipLaunchKernelGGL(poly_mfma_kernel, dim3(BLOCKS), dim3(256), 0, stream,
                     param, coeffs, ws);
  hipLaunchKernelGGL(poly_reduce_kernel, dim3(NB), dim3(256), 0, stream, ws,
                     out);
}